// Round 12
// baseline (185.289 us; speedup 1.0000x reference)
//
#include <hip/hip_runtime.h>
#include <stdint.h>

typedef __bf16 bf16;
typedef __bf16 bf16x4 __attribute__((ext_vector_type(4)));
typedef __bf16 bf16x8 __attribute__((ext_vector_type(8)));
typedef float f32x4 __attribute__((ext_vector_type(4)));

#define TSEQ 2048
#define NHEAD 16
#define HDIM 64
#define CDIM 1024

#define AS1(p) ((const __attribute__((address_space(1))) void*)(p))
#define AS3(p) ((__attribute__((address_space(3))) void*)(p))

#if __has_builtin(__builtin_amdgcn_exp2f)
#define EXP2(x) __builtin_amdgcn_exp2f(x)
#else
#define EXP2(x) exp2f(x)
#endif

// ---------------- fp32 -> bf16 cast of x, Wqkv, Wout in ONE launch -----------
__global__ __launch_bounds__(256) void cast3_bf16(const float* __restrict__ in1, int n1,
                                                  const float* __restrict__ in2, int n2,
                                                  const float* __restrict__ in3, int n3,
                                                  bf16* __restrict__ out1,
                                                  bf16* __restrict__ out2,
                                                  bf16* __restrict__ out3) {
  int i = (blockIdx.x * 256 + threadIdx.x) * 8;
  const float* src;
  bf16* dst;
  if (i < n1) {
    src = in1 + i; dst = out1 + i;
  } else if (i < n1 + n2) {
    src = in2 + (i - n1); dst = out2 + (i - n1);
  } else if (i < n1 + n2 + n3) {
    src = in3 + (i - n1 - n2); dst = out3 + (i - n1 - n2);
  } else {
    return;
  }
  float4 a = *(const float4*)src;
  float4 b = *(const float4*)(src + 4);
  bf16x8 r;
  r[0] = (bf16)a.x; r[1] = (bf16)a.y; r[2] = (bf16)a.z; r[3] = (bf16)a.w;
  r[4] = (bf16)b.x; r[5] = (bf16)b.y; r[6] = (bf16)b.z; r[7] = (bf16)b.w;
  *(bf16x8*)dst = r;
}

// ---------------- GEMM1 + fused RoPE + fused V-transpose ---------------------
// R12: counted-vmcnt pipeline (T4, m218) on the R7-verified loop. 3 LDS
// buffers (48KB); iteration it computes buf it%3 while staging tile it+2.
// Barrier = s_waitcnt vmcnt(4) lgkmcnt(0) + raw s_barrier: the next tile's 4
// gload_lds stay IN FLIGHT across the barrier (m97's ~20% stall was the
// compiler's vmcnt(0) drain before s_barrier). lgkmcnt(0) closes the
// rule-#18 WAR hazard (ds_reads outstanding while another wave overwrites
// the buffer). Epilogue of the pipeline drains vmcnt(0) at it=30.
// Fragment reads / MFMA / rope / V-transpose epilogue: byte-identical to R7.
__global__ __launch_bounds__(256) void gemm_qkv_rope(const bf16* __restrict__ A,
                                                     const bf16* __restrict__ B,
                                                     const float* __restrict__ cosb,
                                                     const float* __restrict__ sinb,
                                                     bf16* __restrict__ Qb,
                                                     bf16* __restrict__ Kb,
                                                     bf16* __restrict__ Vt) {
  constexpr int K = 1024;
  __shared__ bf16 smem[24576];  // 3 x (A 4096 + B 4096)
  const int t = threadIdx.x;
  const int w = t >> 6, l = t & 63, g = l >> 4, ln = l & 15;
  const int wm = (w >> 1) * 64, wn = (w & 1) * 64;
  const int m0 = blockIdx.x * 128, n0 = blockIdx.y * 128;
  const int r0 = t >> 2, kc0 = (t & 3) * 8;

  f32x4 acc[4][4] = {};

#define STAGE_G1(buf, k0)                                                             \
  do {                                                                                \
    __builtin_amdgcn_global_load_lds(AS1(A + (size_t)(m0 + r0) * K + (k0) + kc0),     \
                                     AS3(&smem[(buf) * 8192 + t * 8]), 16, 0, 0);     \
    __builtin_amdgcn_global_load_lds(AS1(A + (size_t)(m0 + r0 + 64) * K + (k0) + kc0),\
                                     AS3(&smem[(buf) * 8192 + (t + 256) * 8]), 16, 0, 0); \
    __builtin_amdgcn_global_load_lds(AS1(B + (size_t)(n0 + r0) * K + (k0) + kc0),     \
                                     AS3(&smem[(buf) * 8192 + 4096 + t * 8]), 16, 0, 0);  \
    __builtin_amdgcn_global_load_lds(AS1(B + (size_t)(n0 + r0 + 64) * K + (k0) + kc0),\
                                     AS3(&smem[(buf) * 8192 + 4096 + (t + 256) * 8]), 16, 0, 0); \
  } while (0)

  // prologue: tiles 0 and 1 in flight; wait for tile 0 only (4 newest stay out)
  STAGE_G1(0, 0);
  STAGE_G1(1, 32);
  asm volatile("s_waitcnt vmcnt(4) lgkmcnt(0)" ::: "memory");
  __builtin_amdgcn_s_barrier();
  asm volatile("" ::: "memory");

  for (int it = 0; it < 32; ++it) {
    const int cur = it % 3;
    if (it < 30) STAGE_G1((it + 2) % 3, (it + 2) * 32);
    const bf16* sa = &smem[cur * 8192];
    const bf16* sb = &smem[cur * 8192 + 4096];
    bf16x8 af[4], bfr[4];
#pragma unroll
    for (int i = 0; i < 4; i++) {
      af[i] = *(const bf16x8*)&sa[(wm + i * 16 + ln) * 32 + g * 8];
      bfr[i] = *(const bf16x8*)&sb[(wn + i * 16 + ln) * 32 + g * 8];
    }
#pragma unroll
    for (int i = 0; i < 4; i++)
#pragma unroll
      for (int j = 0; j < 4; j++)
        acc[i][j] = __builtin_amdgcn_mfma_f32_16x16x32_bf16(af[i], bfr[j], acc[i][j], 0, 0, 0);
    if (it < 30) {
      // next tile resident after this; tile it+2's 4 loads stay in flight
      asm volatile("s_waitcnt vmcnt(4) lgkmcnt(0)" ::: "memory");
      __builtin_amdgcn_s_barrier();
      asm volatile("" ::: "memory");
    } else if (it == 30) {
      asm volatile("s_waitcnt vmcnt(0) lgkmcnt(0)" ::: "memory");
      __builtin_amdgcn_s_barrier();
      asm volatile("" ::: "memory");
    }
  }
#undef STAGE_G1

  const int part = n0 >> 10;  // 0=Q, 1=K, 2=V (uniform per block)
  if (part < 2) {
    bf16* dst = part ? Kb : Qb;
    const float qs = part ? 1.0f : 0.18033688011112042f;  // 0.125*log2(e) into Q
#pragma unroll
    for (int i = 0; i < 4; i++)
#pragma unroll
      for (int j = 0; j < 2; j++) {  // acc[i][j] = x1, acc[i][j+2] = x2 (col+32)
        int nl = (n0 & 1023) + wn + j * 16 + ln;
        int h = nl >> 6, d = nl & 31;
#pragma unroll
        for (int r = 0; r < 4; r++) {
          int row = m0 + wm + i * 16 + g * 4 + r;
          int tok = row & (TSEQ - 1), bb = row >> 11;
          float c = cosb[tok * 32 + d], s = sinb[tok * 32 + d];
          float a1 = acc[i][j][r], a2 = acc[i][j + 2][r];
          size_t ob = ((size_t)(bb * NHEAD + h) * TSEQ + tok) * HDIM + d;
          dst[ob] = (bf16)((a1 * c - a2 * s) * qs);
          dst[ob + 32] = (bf16)((a2 * c + a1 * s) * qs);
        }
      }
  } else {
    // V: transpose this block's 128(t) x 128(n) tile -> Vt[b,h,d,t]
    const int bb = m0 >> 11;
    const int tbase = m0 & (TSEQ - 1);
    const int nbase = n0 - 2048;
#pragma unroll
    for (int pass = 0; pass < 2; pass++) {
      __syncthreads();  // full drain; smem (incl. last-read buffer) now free
      if ((w >> 1) == pass) {  // waves owning this t-half write their acc
#pragma unroll
        for (int i = 0; i < 4; i++)
#pragma unroll
          for (int j = 0; j < 4; j++) {
            int lr = i * 16 + g * 4;
            int lc = wn + j * 16 + ln;
#pragma unroll
            for (int r = 0; r < 4; r++)
              smem[(lr + r) * 132 + lc] = (bf16)acc[i][j][r];
          }
      }
      __syncthreads();
      for (int c = t; c < 1024; c += 256) {  // 128 channels x 8 t-chunks
        int ch = c >> 3, tc = c & 7;
        bf16x8 o;
#pragma unroll
        for (int j2 = 0; j2 < 8; j2++) o[j2] = smem[(tc * 8 + j2) * 132 + ch];
        int n = nbase + ch;
        int h = n >> 6, d = n & 63;
        *(bf16x8*)(Vt + ((size_t)((bb * NHEAD + h) * HDIM + d)) * TSEQ +
                   tbase + pass * 64 + tc * 8) = o;
      }
    }
  }
}

// ---------------- GEMM (out-proj): 128x128 tile (gemm1's verified K-loop) ----
// R11 version, unchanged (kept stable to isolate the gemm1 pipeline change).
__global__ __launch_bounds__(256) void gemm_out(const bf16* __restrict__ A,
                                                const bf16* __restrict__ B,
                                                float* __restrict__ C,
                                                int M, int N, int K) {
  __shared__ bf16 smem[8192];
  const int t = threadIdx.x;
  const int w = t >> 6, l = t & 63, g = l >> 4, ln = l & 15;
  const int wm = (w >> 1) * 64, wn = (w & 1) * 64;
  const int m0 = blockIdx.x * 128, n0 = blockIdx.y * 128;
  const int r0 = t >> 2, kc0 = (t & 3) * 8;

  f32x4 acc[4][4] = {};

  for (int k0 = 0; k0 < K; k0 += 32) {
    __syncthreads();
    __builtin_amdgcn_global_load_lds(AS1(A + (size_t)(m0 + r0) * K + k0 + kc0),
                                     AS3(&smem[t * 8]), 16, 0, 0);
    __builtin_amdgcn_global_load_lds(AS1(A + (size_t)(m0 + r0 + 64) * K + k0 + kc0),
                                     AS3(&smem[(t + 256) * 8]), 16, 0, 0);
    __builtin_amdgcn_global_load_lds(AS1(B + (size_t)(n0 + r0) * K + k0 + kc0),
                                     AS3(&smem[4096 + t * 8]), 16, 0, 0);
    __builtin_amdgcn_global_load_lds(AS1(B + (size_t)(n0 + r0 + 64) * K + k0 + kc0),
                                     AS3(&smem[4096 + (t + 256) * 8]), 16, 0, 0);
    __syncthreads();
    bf16x8 af[4], bfr[4];
#pragma unroll
    for (int i = 0; i < 4; i++) {
      af[i] = *(const bf16x8*)&smem[(wm + i * 16 + ln) * 32 + g * 8];
      bfr[i] = *(const bf16x8*)&smem[4096 + (wn + i * 16 + ln) * 32 + g * 8];
    }
#pragma unroll
    for (int i = 0; i < 4; i++)
#pragma unroll
      for (int j = 0; j < 4; j++)
        acc[i][j] = __builtin_amdgcn_mfma_f32_16x16x32_bf16(af[i], bfr[j], acc[i][j], 0, 0, 0);
  }
#pragma unroll
  for (int i = 0; i < 4; i++)
#pragma unroll
    for (int j = 0; j < 4; j++) {
      int row = m0 + wm + i * 16 + g * 4;
      int col = n0 + wn + j * 16 + ln;
#pragma unroll
      for (int r = 0; r < 4; r++)
        C[(size_t)(row + r) * N + col] = acc[i][j][r];
    }
}

// ---------------- Flash attention (causal), split-k x2, no-max exp2 ----------
// R7-EXACT version (best measured total: 180.3us). 2-subtile variants closed
// after three losses (R5 occupancy, R9 spills, R10 clean-but-slower).
__global__ __launch_bounds__(1024, 4) void attn_fwd(const bf16* __restrict__ Q,
                                                    const bf16* __restrict__ K,
                                                    const bf16* __restrict__ Vt,
                                                    bf16* __restrict__ ctx) {
  __shared__ __align__(16) char smem_raw[65536];
  bf16* Ks = (bf16*)smem_raw;                   // [2][64*64]  16KB
  bf16* VTs = (bf16*)(smem_raw + 16384);        // [2][64*64]  16KB
  bf16* Ps = (bf16*)(smem_raw + 32768);         // [16][16*64] 32KB
  float* Mbuf = (float*)smem_raw;               // overlay, merge phase (32KB)
  float* Lbuf = (float*)(smem_raw + 32768);     // overlay, merge phase (2KB)

  const int t = threadIdx.x;
  const int w = t >> 6;                 // wave 0..15
  const int p = w >> 3;                 // parity group 0/1
  const int wq = w & 7;                 // q-subwave 0..7 (16 rows each)
  const int l = t & 63, g = l >> 4, ln = l & 15;
  const int bid = blockIdx.x;
  const int bh = bid & 31;              // head-locality: XCD = bh & 7
  const int qb0 = 15 - (bid >> 5);      // LPT: longest blocks first
  const size_t base = (size_t)bh * TSEQ * HDIM;

  const int q0 = qb0 * 128;
  const int qwb = q0 + wq * 16;         // this wave's q base
  const int dtile = qwb >> 6;           // = 2*qb0 + (wq>>2)
  const int q_g = qwb + ln;
  const int lswz = (ln & 7) * 8;        // read-side xor operand (elements)

  // staging: threads [0,512) stage group0's tile, [512,1024) group1's.
  const int ts = t >> 9;                // == p for this thread's waves
  const int tt = t & 511;
  const int r0 = tt >> 3, ch0 = (tt & 7) * 8;
  const int sidx = r0 * 64 + (((tt & 7) ^ (r0 & 7)) * 8);  // swizzled dst

  bf16x8 bq[2];
  bq[0] = *(const bf16x8*)(Q + base + (size_t)q_g * HDIM + g * 8);
  bq[1] = *(const bf16x8*)(Q + base + (size_t)q_g * HDIM + 32 + g * 8);

  // my group's tile sequence: kt = 2i + ts -> rows ts*64 + r0 + i*128
  const bf16* kp = K + base + (size_t)(ts * 64 + r0) * HDIM + ch0;
  const bf16* vp = Vt + base + (size_t)r0 * TSEQ + ts * 64 + ch0;
  bf16x8 kr = *(const bf16x8*)kp;
  bf16x8 vr = *(const bf16x8*)vp;

  f32x4 acc[4] = {};
  float l_run = 0.f;

  for (int i = 0; i <= qb0; i++) {
    __syncthreads();  // prev tiles' readers done
    *(bf16x8*)&Ks[ts * 4096 + sidx] = kr;
    *(bf16x8*)&VTs[ts * 4096 + sidx] = vr;
    __syncthreads();  // tiles visible
    if (i < qb0) {    // prefetch my group's next tile (rows +128)
      kr = *(const bf16x8*)(kp + (size_t)(i + 1) * 128 * HDIM);
      vr = *(const bf16x8*)(vp + (i + 1) * 128);
    }
    const int kt = 2 * i + p;
    if (kt <= dtile) {  // wave-uniform predicate (no barrier inside)
      f32x4 st[4] = {};
      __builtin_amdgcn_s_setprio(1);
#pragma unroll
      for (int step = 0; step < 2; step++)
#pragma unroll
        for (int mt = 0; mt < 4; mt++) {
          bf16x8 ak = *(const bf16x8*)&Ks[p * 4096 + (mt * 16 + ln) * 64 +
                                          ((step * 32 + g * 8) ^ lswz)];
          st[mt] = __builtin_amdgcn_mfma_f32_16x16x32_bf16(ak, bq[step], st[mt], 0, 0, 0);
        }
      __builtin_amdgcn_s_setprio(0);
      float vals[16];
      if (kt == dtile) {
#pragma unroll
        for (int mt = 0; mt < 4; mt++)
#pragma unroll
          for (int r = 0; r < 4; r++) {
            int kg = kt * 64 + mt * 16 + g * 4 + r;
            vals[mt * 4 + r] = (kg <= q_g) ? st[mt][r] : -INFINITY;
          }
      } else {
#pragma unroll
        for (int mt = 0; mt < 4; mt++)
#pragma unroll
          for (int r = 0; r < 4; r++) vals[mt * 4 + r] = st[mt][r];
      }
      float psum = 0.f;
#pragma unroll
      for (int i2 = 0; i2 < 16; i2++) {
        float pv = EXP2(vals[i2]);
        vals[i2] = pv;
        psum += pv;
      }
      psum += __shfl_xor(psum, 16);
      psum += __shfl_xor(psum, 32);
      l_run += psum;
#pragma unroll
      for (int mt = 0; mt < 4; mt++) {
        bf16x4 pk;
#pragma unroll
        for (int r = 0; r < 4; r++) pk[r] = (bf16)vals[mt * 4 + r];
        // k-col = mt*16 + g*4 -> col8 = mt*2 + (g>>1); swizzle col8 by ln&7
        *(bf16x4*)&Ps[w * 1024 + ln * 64 +
                      (((mt * 16 + (g >> 1) * 8) ^ lswz) + (g & 1) * 4)] = pk;
      }
      __builtin_amdgcn_s_setprio(1);
#pragma unroll
      for (int step = 0; step < 2; step++) {
        bf16x8 ap = *(const bf16x8*)&Ps[w * 1024 + ln * 64 + ((step * 32 + g * 8) ^ lswz)];
#pragma unroll
        for (int nt = 0; nt < 4; nt++) {
          bf16x8 bv = *(const bf16x8*)&VTs[p * 4096 + (nt * 16 + ln) * 64 +
                                           ((step * 32 + g * 8) ^ lswz)];
          acc[nt] = __builtin_amdgcn_mfma_f32_16x16x32_bf16(ap, bv, acc[nt], 0, 0, 0);
        }
      }
      __builtin_amdgcn_s_setprio(0);
    }
  }

  // ---- merge the two parity groups (overlay on dead K/V/Ps LDS) ----
  __syncthreads();  // loop reads done; staging area dead
  if (p == 1) {
#pragma unroll
    for (int nt = 0; nt < 4; nt++)
      *(f32x4*)&Mbuf[(wq * 64 + l) * 16 + nt * 4] = acc[nt];
    Lbuf[wq * 64 + l] = l_run;
  }
  __syncthreads();
  if (p == 0) {
#pragma unroll
    for (int nt = 0; nt < 4; nt++) acc[nt] += *(const f32x4*)&Mbuf[(wq * 64 + l) * 16 + nt * 4];
    l_run += Lbuf[wq * 64 + l];
    float inv = 1.0f / l_run;  // all 4 g-copies of a given ln hold the sum
    float lrow[4];
#pragma unroll
    for (int r = 0; r < 4; r++) lrow[r] = __shfl(inv, g * 4 + r, 64);
    const int b = bh >> 4, h = bh & (NHEAD - 1);
#pragma unroll
    for (int nt = 0; nt < 4; nt++)
#pragma unroll
      for (int r = 0; r < 4; r++) {
        int q = qwb + g * 4 + r;
        ctx[(size_t)(b * TSEQ + q) * CDIM + h * HDIM + nt * 16 + ln] =
            (bf16)(acc[nt][r] * lrow[r]);
      }
  }
}

extern "C" void kernel_launch(void* const* d_in, const int* in_sizes, int n_in,
                              void* d_out, int out_size, void* d_ws, size_t ws_size,
                              hipStream_t stream) {
  const float* x = (const float*)d_in[0];
  const float* cosb = (const float*)d_in[1];
  const float* sinb = (const float*)d_in[2];
  // d_in[3] = mask (bool) — unused; causality derived from indices
  const float* Wqkv = (const float*)d_in[4];
  const float* Wout = (const float*)d_in[5];
  float* out = (float*)d_out;

  // ws layout (42 MB):
  //  [0,8M)          x_bf -> ctx (x_bf dead after gemm1)
  //  [8M,14M)        Wqkv_bf (dead after gemm1)
  //  [14M,16M)       Wout_bf (live until gemm_out)
  //  [16M,24M)       Qb    [24M,32M) Kb    [32M,40M) Vt
  char* ws = (char*)d_ws;
  bf16* x_bf = (bf16*)ws;
  bf16* ctx = (bf16*)ws;
  bf16* Wqkv_bf = (bf16*)(ws + 8388608);
  bf16* Wout_bf = (bf16*)(ws + 14680064);
  bf16* Qb = (bf16*)(ws + 16777216);
  bf16* Kb = (bf16*)(ws + 25165824);
  bf16* Vt = (bf16*)(ws + 33554432);

  // one cast launch for all three fp32 inputs
  cast3_bf16<<<(4194304 + 3145728 + 1048576) / 8 / 256, 256, 0, stream>>>(
      x, 4194304, Wqkv, 3145728, Wout, 1048576, x_bf, Wqkv_bf, Wout_bf);
  // gemm1 + rope + V-transpose fused (counted-vmcnt pipeline)
  gemm_qkv_rope<<<dim3(32, 24), 256, 0, stream>>>(x_bf, Wqkv_bf, cosb, sinb, Qb, Kb, Vt);
  // causal flash attention, split-k x2 -> ctx [B*T, C] (overwrites x_bf)
  attn_fwd<<<512, 1024, 0, stream>>>(Qb, Kb, Vt, ctx);
  // out = ctx @ Wout^T (fp32 out), 128^2 tile
  gemm_out<<<dim3(32, 8), 256, 0, stream>>>(ctx, Wout_bf, out, 4096, 1024, 1024);
}

// Round 13
// 178.179 us; speedup vs baseline: 1.0399x; 1.0399x over previous
//
#include <hip/hip_runtime.h>
#include <stdint.h>

typedef __bf16 bf16;
typedef __bf16 bf16x4 __attribute__((ext_vector_type(4)));
typedef __bf16 bf16x8 __attribute__((ext_vector_type(8)));
typedef float f32x4 __attribute__((ext_vector_type(4)));

#define TSEQ 2048
#define NHEAD 16
#define HDIM 64
#define CDIM 1024

#define AS1(p) ((const __attribute__((address_space(1))) void*)(p))
#define AS3(p) ((__attribute__((address_space(3))) void*)(p))

#if __has_builtin(__builtin_amdgcn_exp2f)
#define EXP2(x) __builtin_amdgcn_exp2f(x)
#else
#define EXP2(x) exp2f(x)
#endif

// ---------------- fp32 -> bf16 cast of x, Wqkv, Wout in ONE launch -----------
__global__ __launch_bounds__(256) void cast3_bf16(const float* __restrict__ in1, int n1,
                                                  const float* __restrict__ in2, int n2,
                                                  const float* __restrict__ in3, int n3,
                                                  bf16* __restrict__ out1,
                                                  bf16* __restrict__ out2,
                                                  bf16* __restrict__ out3) {
  int i = (blockIdx.x * 256 + threadIdx.x) * 8;
  const float* src;
  bf16* dst;
  if (i < n1) {
    src = in1 + i; dst = out1 + i;
  } else if (i < n1 + n2) {
    src = in2 + (i - n1); dst = out2 + (i - n1);
  } else if (i < n1 + n2 + n3) {
    src = in3 + (i - n1 - n2); dst = out3 + (i - n1 - n2);
  } else {
    return;
  }
  float4 a = *(const float4*)src;
  float4 b = *(const float4*)(src + 4);
  bf16x8 r;
  r[0] = (bf16)a.x; r[1] = (bf16)a.y; r[2] = (bf16)a.z; r[3] = (bf16)a.w;
  r[4] = (bf16)b.x; r[5] = (bf16)b.y; r[6] = (bf16)b.z; r[7] = (bf16)b.w;
  *(bf16x8*)dst = r;
}

// ---------------- GEMM1 + fused RoPE + fused V-transpose ---------------------
// R12-verified: counted-vmcnt pipeline (T4, m218) on the R7 loop. 3 LDS
// buffers (48KB); iteration it computes buf it%3 while staging tile it+2.
// Barrier = s_waitcnt vmcnt(4) lgkmcnt(0) + raw s_barrier: next tile's 4
// gload_lds stay IN FLIGHT across the barrier. 44.6 -> 41.2us measured.
__global__ __launch_bounds__(256) void gemm_qkv_rope(const bf16* __restrict__ A,
                                                     const bf16* __restrict__ B,
                                                     const float* __restrict__ cosb,
                                                     const float* __restrict__ sinb,
                                                     bf16* __restrict__ Qb,
                                                     bf16* __restrict__ Kb,
                                                     bf16* __restrict__ Vt) {
  constexpr int K = 1024;
  __shared__ bf16 smem[24576];  // 3 x (A 4096 + B 4096)
  const int t = threadIdx.x;
  const int w = t >> 6, l = t & 63, g = l >> 4, ln = l & 15;
  const int wm = (w >> 1) * 64, wn = (w & 1) * 64;
  const int m0 = blockIdx.x * 128, n0 = blockIdx.y * 128;
  const int r0 = t >> 2, kc0 = (t & 3) * 8;

  f32x4 acc[4][4] = {};

#define STAGE_G1(buf, k0)                                                             \
  do {                                                                                \
    __builtin_amdgcn_global_load_lds(AS1(A + (size_t)(m0 + r0) * K + (k0) + kc0),     \
                                     AS3(&smem[(buf) * 8192 + t * 8]), 16, 0, 0);     \
    __builtin_amdgcn_global_load_lds(AS1(A + (size_t)(m0 + r0 + 64) * K + (k0) + kc0),\
                                     AS3(&smem[(buf) * 8192 + (t + 256) * 8]), 16, 0, 0); \
    __builtin_amdgcn_global_load_lds(AS1(B + (size_t)(n0 + r0) * K + (k0) + kc0),     \
                                     AS3(&smem[(buf) * 8192 + 4096 + t * 8]), 16, 0, 0);  \
    __builtin_amdgcn_global_load_lds(AS1(B + (size_t)(n0 + r0 + 64) * K + (k0) + kc0),\
                                     AS3(&smem[(buf) * 8192 + 4096 + (t + 256) * 8]), 16, 0, 0); \
  } while (0)

  // prologue: tiles 0 and 1 in flight; wait for tile 0 only (4 newest stay out)
  STAGE_G1(0, 0);
  STAGE_G1(1, 32);
  asm volatile("s_waitcnt vmcnt(4) lgkmcnt(0)" ::: "memory");
  __builtin_amdgcn_s_barrier();
  asm volatile("" ::: "memory");

  for (int it = 0; it < 32; ++it) {
    const int cur = it % 3;
    if (it < 30) STAGE_G1((it + 2) % 3, (it + 2) * 32);
    const bf16* sa = &smem[cur * 8192];
    const bf16* sb = &smem[cur * 8192 + 4096];
    bf16x8 af[4], bfr[4];
#pragma unroll
    for (int i = 0; i < 4; i++) {
      af[i] = *(const bf16x8*)&sa[(wm + i * 16 + ln) * 32 + g * 8];
      bfr[i] = *(const bf16x8*)&sb[(wn + i * 16 + ln) * 32 + g * 8];
    }
#pragma unroll
    for (int i = 0; i < 4; i++)
#pragma unroll
      for (int j = 0; j < 4; j++)
        acc[i][j] = __builtin_amdgcn_mfma_f32_16x16x32_bf16(af[i], bfr[j], acc[i][j], 0, 0, 0);
    if (it < 30) {
      asm volatile("s_waitcnt vmcnt(4) lgkmcnt(0)" ::: "memory");
      __builtin_amdgcn_s_barrier();
      asm volatile("" ::: "memory");
    } else if (it == 30) {
      asm volatile("s_waitcnt vmcnt(0) lgkmcnt(0)" ::: "memory");
      __builtin_amdgcn_s_barrier();
      asm volatile("" ::: "memory");
    }
  }
#undef STAGE_G1

  const int part = n0 >> 10;  // 0=Q, 1=K, 2=V (uniform per block)
  if (part < 2) {
    bf16* dst = part ? Kb : Qb;
    const float qs = part ? 1.0f : 0.18033688011112042f;  // 0.125*log2(e) into Q
#pragma unroll
    for (int i = 0; i < 4; i++)
#pragma unroll
      for (int j = 0; j < 2; j++) {  // acc[i][j] = x1, acc[i][j+2] = x2 (col+32)
        int nl = (n0 & 1023) + wn + j * 16 + ln;
        int h = nl >> 6, d = nl & 31;
#pragma unroll
        for (int r = 0; r < 4; r++) {
          int row = m0 + wm + i * 16 + g * 4 + r;
          int tok = row & (TSEQ - 1), bb = row >> 11;
          float c = cosb[tok * 32 + d], s = sinb[tok * 32 + d];
          float a1 = acc[i][j][r], a2 = acc[i][j + 2][r];
          size_t ob = ((size_t)(bb * NHEAD + h) * TSEQ + tok) * HDIM + d;
          dst[ob] = (bf16)((a1 * c - a2 * s) * qs);
          dst[ob + 32] = (bf16)((a2 * c + a1 * s) * qs);
        }
      }
  } else {
    // V: transpose this block's 128(t) x 128(n) tile -> Vt[b,h,d,t]
    const int bb = m0 >> 11;
    const int tbase = m0 & (TSEQ - 1);
    const int nbase = n0 - 2048;
#pragma unroll
    for (int pass = 0; pass < 2; pass++) {
      __syncthreads();  // full drain; smem now free
      if ((w >> 1) == pass) {  // waves owning this t-half write their acc
#pragma unroll
        for (int i = 0; i < 4; i++)
#pragma unroll
          for (int j = 0; j < 4; j++) {
            int lr = i * 16 + g * 4;
            int lc = wn + j * 16 + ln;
#pragma unroll
            for (int r = 0; r < 4; r++)
              smem[(lr + r) * 132 + lc] = (bf16)acc[i][j][r];
          }
      }
      __syncthreads();
      for (int c = t; c < 1024; c += 256) {  // 128 channels x 8 t-chunks
        int ch = c >> 3, tc = c & 7;
        bf16x8 o;
#pragma unroll
        for (int j2 = 0; j2 < 8; j2++) o[j2] = smem[(tc * 8 + j2) * 132 + ch];
        int n = nbase + ch;
        int h = n >> 6, d = n & 63;
        *(bf16x8*)(Vt + ((size_t)((bb * NHEAD + h) * HDIM + d)) * TSEQ +
                   tbase + pass * 64 + tc * 8) = o;
      }
    }
  }
}

// ---------------- GEMM (out-proj): 128x128 tile + counted-vmcnt pipeline -----
// R13: the R12-proven pipeline transform (3 buffers, vmcnt(4)+raw barrier,
// drain at it=30) applied to the R11-verified 128^2 loop. Only the epilogue
// (plain fp32 stores) differs from gemm1. Grid 32x8 = 256 blocks, LDS 48KB.
__global__ __launch_bounds__(256) void gemm_out(const bf16* __restrict__ A,
                                                const bf16* __restrict__ B,
                                                float* __restrict__ C,
                                                int M, int N, int K) {
  __shared__ bf16 smem[24576];  // 3 x (A 4096 + B 4096)
  const int t = threadIdx.x;
  const int w = t >> 6, l = t & 63, g = l >> 4, ln = l & 15;
  const int wm = (w >> 1) * 64, wn = (w & 1) * 64;
  const int m0 = blockIdx.x * 128, n0 = blockIdx.y * 128;
  const int r0 = t >> 2, kc0 = (t & 3) * 8;

  f32x4 acc[4][4] = {};

#define STAGE_GO(buf, k0)                                                             \
  do {                                                                                \
    __builtin_amdgcn_global_load_lds(AS1(A + (size_t)(m0 + r0) * K + (k0) + kc0),     \
                                     AS3(&smem[(buf) * 8192 + t * 8]), 16, 0, 0);     \
    __builtin_amdgcn_global_load_lds(AS1(A + (size_t)(m0 + r0 + 64) * K + (k0) + kc0),\
                                     AS3(&smem[(buf) * 8192 + (t + 256) * 8]), 16, 0, 0); \
    __builtin_amdgcn_global_load_lds(AS1(B + (size_t)(n0 + r0) * K + (k0) + kc0),     \
                                     AS3(&smem[(buf) * 8192 + 4096 + t * 8]), 16, 0, 0);  \
    __builtin_amdgcn_global_load_lds(AS1(B + (size_t)(n0 + r0 + 64) * K + (k0) + kc0),\
                                     AS3(&smem[(buf) * 8192 + 4096 + (t + 256) * 8]), 16, 0, 0); \
  } while (0)

  STAGE_GO(0, 0);
  STAGE_GO(1, 32);
  asm volatile("s_waitcnt vmcnt(4) lgkmcnt(0)" ::: "memory");
  __builtin_amdgcn_s_barrier();
  asm volatile("" ::: "memory");

  for (int it = 0; it < 32; ++it) {
    const int cur = it % 3;
    if (it < 30) STAGE_GO((it + 2) % 3, (it + 2) * 32);
    const bf16* sa = &smem[cur * 8192];
    const bf16* sb = &smem[cur * 8192 + 4096];
    bf16x8 af[4], bfr[4];
#pragma unroll
    for (int i = 0; i < 4; i++) {
      af[i] = *(const bf16x8*)&sa[(wm + i * 16 + ln) * 32 + g * 8];
      bfr[i] = *(const bf16x8*)&sb[(wn + i * 16 + ln) * 32 + g * 8];
    }
#pragma unroll
    for (int i = 0; i < 4; i++)
#pragma unroll
      for (int j = 0; j < 4; j++)
        acc[i][j] = __builtin_amdgcn_mfma_f32_16x16x32_bf16(af[i], bfr[j], acc[i][j], 0, 0, 0);
    if (it < 30) {
      asm volatile("s_waitcnt vmcnt(4) lgkmcnt(0)" ::: "memory");
      __builtin_amdgcn_s_barrier();
      asm volatile("" ::: "memory");
    } else if (it == 30) {
      asm volatile("s_waitcnt vmcnt(0) lgkmcnt(0)" ::: "memory");
      __builtin_amdgcn_s_barrier();
      asm volatile("" ::: "memory");
    }
  }
#undef STAGE_GO

#pragma unroll
  for (int i = 0; i < 4; i++)
#pragma unroll
    for (int j = 0; j < 4; j++) {
      int row = m0 + wm + i * 16 + g * 4;
      int col = n0 + wn + j * 16 + ln;
#pragma unroll
      for (int r = 0; r < 4; r++)
        C[(size_t)(row + r) * N + col] = acc[i][j][r];
    }
}

// ---------------- Flash attention (causal), split-k x2, no-max exp2 ----------
// R7-EXACT version (best measured). 2-subtile variants closed after three
// losses (R5 occupancy, R9 spills, R10 clean-but-slower).
__global__ __launch_bounds__(1024, 4) void attn_fwd(const bf16* __restrict__ Q,
                                                    const bf16* __restrict__ K,
                                                    const bf16* __restrict__ Vt,
                                                    bf16* __restrict__ ctx) {
  __shared__ __align__(16) char smem_raw[65536];
  bf16* Ks = (bf16*)smem_raw;                   // [2][64*64]  16KB
  bf16* VTs = (bf16*)(smem_raw + 16384);        // [2][64*64]  16KB
  bf16* Ps = (bf16*)(smem_raw + 32768);         // [16][16*64] 32KB
  float* Mbuf = (float*)smem_raw;               // overlay, merge phase (32KB)
  float* Lbuf = (float*)(smem_raw + 32768);     // overlay, merge phase (2KB)

  const int t = threadIdx.x;
  const int w = t >> 6;                 // wave 0..15
  const int p = w >> 3;                 // parity group 0/1
  const int wq = w & 7;                 // q-subwave 0..7 (16 rows each)
  const int l = t & 63, g = l >> 4, ln = l & 15;
  const int bid = blockIdx.x;
  const int bh = bid & 31;              // head-locality: XCD = bh & 7
  const int qb0 = 15 - (bid >> 5);      // LPT: longest blocks first
  const size_t base = (size_t)bh * TSEQ * HDIM;

  const int q0 = qb0 * 128;
  const int qwb = q0 + wq * 16;         // this wave's q base
  const int dtile = qwb >> 6;           // = 2*qb0 + (wq>>2)
  const int q_g = qwb + ln;
  const int lswz = (ln & 7) * 8;        // read-side xor operand (elements)

  // staging: threads [0,512) stage group0's tile, [512,1024) group1's.
  const int ts = t >> 9;                // == p for this thread's waves
  const int tt = t & 511;
  const int r0 = tt >> 3, ch0 = (tt & 7) * 8;
  const int sidx = r0 * 64 + (((tt & 7) ^ (r0 & 7)) * 8);  // swizzled dst

  bf16x8 bq[2];
  bq[0] = *(const bf16x8*)(Q + base + (size_t)q_g * HDIM + g * 8);
  bq[1] = *(const bf16x8*)(Q + base + (size_t)q_g * HDIM + 32 + g * 8);

  // my group's tile sequence: kt = 2i + ts -> rows ts*64 + r0 + i*128
  const bf16* kp = K + base + (size_t)(ts * 64 + r0) * HDIM + ch0;
  const bf16* vp = Vt + base + (size_t)r0 * TSEQ + ts * 64 + ch0;
  bf16x8 kr = *(const bf16x8*)kp;
  bf16x8 vr = *(const bf16x8*)vp;

  f32x4 acc[4] = {};
  float l_run = 0.f;

  for (int i = 0; i <= qb0; i++) {
    __syncthreads();  // prev tiles' readers done
    *(bf16x8*)&Ks[ts * 4096 + sidx] = kr;
    *(bf16x8*)&VTs[ts * 4096 + sidx] = vr;
    __syncthreads();  // tiles visible
    if (i < qb0) {    // prefetch my group's next tile (rows +128)
      kr = *(const bf16x8*)(kp + (size_t)(i + 1) * 128 * HDIM);
      vr = *(const bf16x8*)(vp + (i + 1) * 128);
    }
    const int kt = 2 * i + p;
    if (kt <= dtile) {  // wave-uniform predicate (no barrier inside)
      f32x4 st[4] = {};
      __builtin_amdgcn_s_setprio(1);
#pragma unroll
      for (int step = 0; step < 2; step++)
#pragma unroll
        for (int mt = 0; mt < 4; mt++) {
          bf16x8 ak = *(const bf16x8*)&Ks[p * 4096 + (mt * 16 + ln) * 64 +
                                          ((step * 32 + g * 8) ^ lswz)];
          st[mt] = __builtin_amdgcn_mfma_f32_16x16x32_bf16(ak, bq[step], st[mt], 0, 0, 0);
        }
      __builtin_amdgcn_s_setprio(0);
      float vals[16];
      if (kt == dtile) {
#pragma unroll
        for (int mt = 0; mt < 4; mt++)
#pragma unroll
          for (int r = 0; r < 4; r++) {
            int kg = kt * 64 + mt * 16 + g * 4 + r;
            vals[mt * 4 + r] = (kg <= q_g) ? st[mt][r] : -INFINITY;
          }
      } else {
#pragma unroll
        for (int mt = 0; mt < 4; mt++)
#pragma unroll
          for (int r = 0; r < 4; r++) vals[mt * 4 + r] = st[mt][r];
      }
      float psum = 0.f;
#pragma unroll
      for (int i2 = 0; i2 < 16; i2++) {
        float pv = EXP2(vals[i2]);
        vals[i2] = pv;
        psum += pv;
      }
      psum += __shfl_xor(psum, 16);
      psum += __shfl_xor(psum, 32);
      l_run += psum;
#pragma unroll
      for (int mt = 0; mt < 4; mt++) {
        bf16x4 pk;
#pragma unroll
        for (int r = 0; r < 4; r++) pk[r] = (bf16)vals[mt * 4 + r];
        // k-col = mt*16 + g*4 -> col8 = mt*2 + (g>>1); swizzle col8 by ln&7
        *(bf16x4*)&Ps[w * 1024 + ln * 64 +
                      (((mt * 16 + (g >> 1) * 8) ^ lswz) + (g & 1) * 4)] = pk;
      }
      __builtin_amdgcn_s_setprio(1);
#pragma unroll
      for (int step = 0; step < 2; step++) {
        bf16x8 ap = *(const bf16x8*)&Ps[w * 1024 + ln * 64 + ((step * 32 + g * 8) ^ lswz)];
#pragma unroll
        for (int nt = 0; nt < 4; nt++) {
          bf16x8 bv = *(const bf16x8*)&VTs[p * 4096 + (nt * 16 + ln) * 64 +
                                           ((step * 32 + g * 8) ^ lswz)];
          acc[nt] = __builtin_amdgcn_mfma_f32_16x16x32_bf16(ap, bv, acc[nt], 0, 0, 0);
        }
      }
      __builtin_amdgcn_s_setprio(0);
    }
  }

  // ---- merge the two parity groups (overlay on dead K/V/Ps LDS) ----
  __syncthreads();  // loop reads done; staging area dead
  if (p == 1) {
#pragma unroll
    for (int nt = 0; nt < 4; nt++)
      *(f32x4*)&Mbuf[(wq * 64 + l) * 16 + nt * 4] = acc[nt];
    Lbuf[wq * 64 + l] = l_run;
  }
  __syncthreads();
  if (p == 0) {
#pragma unroll
    for (int nt = 0; nt < 4; nt++) acc[nt] += *(const f32x4*)&Mbuf[(wq * 64 + l) * 16 + nt * 4];
    l_run += Lbuf[wq * 64 + l];
    float inv = 1.0f / l_run;  // all 4 g-copies of a given ln hold the sum
    float lrow[4];
#pragma unroll
    for (int r = 0; r < 4; r++) lrow[r] = __shfl(inv, g * 4 + r, 64);
    const int b = bh >> 4, h = bh & (NHEAD - 1);
#pragma unroll
    for (int nt = 0; nt < 4; nt++)
#pragma unroll
      for (int r = 0; r < 4; r++) {
        int q = qwb + g * 4 + r;
        ctx[(size_t)(b * TSEQ + q) * CDIM + h * HDIM + nt * 16 + ln] =
            (bf16)(acc[nt][r] * lrow[r]);
      }
  }
}

extern "C" void kernel_launch(void* const* d_in, const int* in_sizes, int n_in,
                              void* d_out, int out_size, void* d_ws, size_t ws_size,
                              hipStream_t stream) {
  const float* x = (const float*)d_in[0];
  const float* cosb = (const float*)d_in[1];
  const float* sinb = (const float*)d_in[2];
  // d_in[3] = mask (bool) — unused; causality derived from indices
  const float* Wqkv = (const float*)d_in[4];
  const float* Wout = (const float*)d_in[5];
  float* out = (float*)d_out;

  // ws layout (42 MB):
  //  [0,8M)          x_bf -> ctx (x_bf dead after gemm1)
  //  [8M,14M)        Wqkv_bf (dead after gemm1)
  //  [14M,16M)       Wout_bf (live until gemm_out)
  //  [16M,24M)       Qb    [24M,32M) Kb    [32M,40M) Vt
  char* ws = (char*)d_ws;
  bf16* x_bf = (bf16*)ws;
  bf16* ctx = (bf16*)ws;
  bf16* Wqkv_bf = (bf16*)(ws + 8388608);
  bf16* Wout_bf = (bf16*)(ws + 14680064);
  bf16* Qb = (bf16*)(ws + 16777216);
  bf16* Kb = (bf16*)(ws + 25165824);
  bf16* Vt = (bf16*)(ws + 33554432);

  // one cast launch for all three fp32 inputs
  cast3_bf16<<<(4194304 + 3145728 + 1048576) / 8 / 256, 256, 0, stream>>>(
      x, 4194304, Wqkv, 3145728, Wout, 1048576, x_bf, Wqkv_bf, Wout_bf);
  // gemm1 + rope + V-transpose fused (counted-vmcnt pipeline)
  gemm_qkv_rope<<<dim3(32, 24), 256, 0, stream>>>(x_bf, Wqkv_bf, cosb, sinb, Qb, Kb, Vt);
  // causal flash attention, split-k x2 -> ctx [B*T, C] (overwrites x_bf)
  attn_fwd<<<512, 1024, 0, stream>>>(Qb, Kb, Vt, ctx);
  // out = ctx @ Wout^T (fp32 out), 128^2 tile + counted-vmcnt pipeline
  gemm_out<<<dim3(32, 8), 256, 0, stream>>>(ctx, Wout_bf, out, 4096, 1024, 1024);
}

// Round 14
// 175.545 us; speedup vs baseline: 1.0555x; 1.0150x over previous
//
#include <hip/hip_runtime.h>
#include <stdint.h>

typedef __bf16 bf16;
typedef __bf16 bf16x4 __attribute__((ext_vector_type(4)));
typedef __bf16 bf16x8 __attribute__((ext_vector_type(8)));
typedef float f32x4 __attribute__((ext_vector_type(4)));

#define TSEQ 2048
#define NHEAD 16
#define HDIM 64
#define CDIM 1024

#define AS1(p) ((const __attribute__((address_space(1))) void*)(p))
#define AS3(p) ((__attribute__((address_space(3))) void*)(p))

#if __has_builtin(__builtin_amdgcn_exp2f)
#define EXP2(x) __builtin_amdgcn_exp2f(x)
#else
#define EXP2(x) exp2f(x)
#endif

// ---------------- fp32 -> bf16 cast of x, Wqkv, Wout in ONE launch -----------
__global__ __launch_bounds__(256) void cast3_bf16(const float* __restrict__ in1, int n1,
                                                  const float* __restrict__ in2, int n2,
                                                  const float* __restrict__ in3, int n3,
                                                  bf16* __restrict__ out1,
                                                  bf16* __restrict__ out2,
                                                  bf16* __restrict__ out3) {
  int i = (blockIdx.x * 256 + threadIdx.x) * 8;
  const float* src;
  bf16* dst;
  if (i < n1) {
    src = in1 + i; dst = out1 + i;
  } else if (i < n1 + n2) {
    src = in2 + (i - n1); dst = out2 + (i - n1);
  } else if (i < n1 + n2 + n3) {
    src = in3 + (i - n1 - n2); dst = out3 + (i - n1 - n2);
  } else {
    return;
  }
  float4 a = *(const float4*)src;
  float4 b = *(const float4*)(src + 4);
  bf16x8 r;
  r[0] = (bf16)a.x; r[1] = (bf16)a.y; r[2] = (bf16)a.z; r[3] = (bf16)a.w;
  r[4] = (bf16)b.x; r[5] = (bf16)b.y; r[6] = (bf16)b.z; r[7] = (bf16)b.w;
  *(bf16x8*)dst = r;
}

// ---------------- GEMM1 + fused RoPE + fused V-transpose ---------------------
// R12-verified counted-vmcnt pipeline (41.2us) + R14 conflict-free chunk
// swizzle. Old layout: all 16 ln-lanes of a read phase use slot g -> 64
// words land in 8 banks (4x over the 2-word/bank floor). Fix (T21 form):
// stage thread t loads global chunk (t&3)^((t>>3)&3) into its UNCHANGED
// linear gload_lds dst; slot s of row r then holds chunk s^h(r), h(r) =
// (r>>1)&3. Reads use slot g^((ln>>1)&3) (row-base terms are == 0 mod 4,
// so h is lane-pure) -> 16 lanes cover all 8 (parity x slot) bank-groups
// twice = conflict-free. Same BK/LDS/occupancy: clean isolation of the
// conflict question (R8's confound removed).
__global__ __launch_bounds__(256) void gemm_qkv_rope(const bf16* __restrict__ A,
                                                     const bf16* __restrict__ B,
                                                     const float* __restrict__ cosb,
                                                     const float* __restrict__ sinb,
                                                     bf16* __restrict__ Qb,
                                                     bf16* __restrict__ Kb,
                                                     bf16* __restrict__ Vt) {
  constexpr int K = 1024;
  __shared__ bf16 smem[24576];  // 3 x (A 4096 + B 4096)
  const int t = threadIdx.x;
  const int w = t >> 6, l = t & 63, g = l >> 4, ln = l & 15;
  const int wm = (w >> 1) * 64, wn = (w & 1) * 64;
  const int m0 = blockIdx.x * 128, n0 = blockIdx.y * 128;
  const int r0 = t >> 2;
  const int kcs = ((t & 3) ^ ((t >> 3) & 3)) * 8;  // pre-swizzled source chunk
  const int rsl = ((ln >> 1) & 3) * 8;             // read-side slot xor (elems)

  f32x4 acc[4][4] = {};

#define STAGE_G1(buf, k0)                                                             \
  do {                                                                                \
    __builtin_amdgcn_global_load_lds(AS1(A + (size_t)(m0 + r0) * K + (k0) + kcs),     \
                                     AS3(&smem[(buf) * 8192 + t * 8]), 16, 0, 0);     \
    __builtin_amdgcn_global_load_lds(AS1(A + (size_t)(m0 + r0 + 64) * K + (k0) + kcs),\
                                     AS3(&smem[(buf) * 8192 + (t + 256) * 8]), 16, 0, 0); \
    __builtin_amdgcn_global_load_lds(AS1(B + (size_t)(n0 + r0) * K + (k0) + kcs),     \
                                     AS3(&smem[(buf) * 8192 + 4096 + t * 8]), 16, 0, 0);  \
    __builtin_amdgcn_global_load_lds(AS1(B + (size_t)(n0 + r0 + 64) * K + (k0) + kcs),\
                                     AS3(&smem[(buf) * 8192 + 4096 + (t + 256) * 8]), 16, 0, 0); \
  } while (0)

  // prologue: tiles 0 and 1 in flight; wait for tile 0 only (4 newest stay out)
  STAGE_G1(0, 0);
  STAGE_G1(1, 32);
  asm volatile("s_waitcnt vmcnt(4) lgkmcnt(0)" ::: "memory");
  __builtin_amdgcn_s_barrier();
  asm volatile("" ::: "memory");

  for (int it = 0; it < 32; ++it) {
    const int cur = it % 3;
    if (it < 30) STAGE_G1((it + 2) % 3, (it + 2) * 32);
    const bf16* sa = &smem[cur * 8192];
    const bf16* sb = &smem[cur * 8192 + 4096];
    bf16x8 af[4], bfr[4];
#pragma unroll
    for (int i = 0; i < 4; i++) {
      af[i] = *(const bf16x8*)&sa[(wm + i * 16 + ln) * 32 + ((g * 8) ^ rsl)];
      bfr[i] = *(const bf16x8*)&sb[(wn + i * 16 + ln) * 32 + ((g * 8) ^ rsl)];
    }
#pragma unroll
    for (int i = 0; i < 4; i++)
#pragma unroll
      for (int j = 0; j < 4; j++)
        acc[i][j] = __builtin_amdgcn_mfma_f32_16x16x32_bf16(af[i], bfr[j], acc[i][j], 0, 0, 0);
    if (it < 30) {
      asm volatile("s_waitcnt vmcnt(4) lgkmcnt(0)" ::: "memory");
      __builtin_amdgcn_s_barrier();
      asm volatile("" ::: "memory");
    } else if (it == 30) {
      asm volatile("s_waitcnt vmcnt(0) lgkmcnt(0)" ::: "memory");
      __builtin_amdgcn_s_barrier();
      asm volatile("" ::: "memory");
    }
  }
#undef STAGE_G1

  const int part = n0 >> 10;  // 0=Q, 1=K, 2=V (uniform per block)
  if (part < 2) {
    bf16* dst = part ? Kb : Qb;
    const float qs = part ? 1.0f : 0.18033688011112042f;  // 0.125*log2(e) into Q
#pragma unroll
    for (int i = 0; i < 4; i++)
#pragma unroll
      for (int j = 0; j < 2; j++) {  // acc[i][j] = x1, acc[i][j+2] = x2 (col+32)
        int nl = (n0 & 1023) + wn + j * 16 + ln;
        int h = nl >> 6, d = nl & 31;
#pragma unroll
        for (int r = 0; r < 4; r++) {
          int row = m0 + wm + i * 16 + g * 4 + r;
          int tok = row & (TSEQ - 1), bb = row >> 11;
          float c = cosb[tok * 32 + d], s = sinb[tok * 32 + d];
          float a1 = acc[i][j][r], a2 = acc[i][j + 2][r];
          size_t ob = ((size_t)(bb * NHEAD + h) * TSEQ + tok) * HDIM + d;
          dst[ob] = (bf16)((a1 * c - a2 * s) * qs);
          dst[ob + 32] = (bf16)((a2 * c + a1 * s) * qs);
        }
      }
  } else {
    // V: transpose this block's 128(t) x 128(n) tile -> Vt[b,h,d,t]
    const int bb = m0 >> 11;
    const int tbase = m0 & (TSEQ - 1);
    const int nbase = n0 - 2048;
#pragma unroll
    for (int pass = 0; pass < 2; pass++) {
      __syncthreads();  // full drain; smem now free
      if ((w >> 1) == pass) {  // waves owning this t-half write their acc
#pragma unroll
        for (int i = 0; i < 4; i++)
#pragma unroll
          for (int j = 0; j < 4; j++) {
            int lr = i * 16 + g * 4;
            int lc = wn + j * 16 + ln;
#pragma unroll
            for (int r = 0; r < 4; r++)
              smem[(lr + r) * 132 + lc] = (bf16)acc[i][j][r];
          }
      }
      __syncthreads();
      for (int c = t; c < 1024; c += 256) {  // 128 channels x 8 t-chunks
        int ch = c >> 3, tc = c & 7;
        bf16x8 o;
#pragma unroll
        for (int j2 = 0; j2 < 8; j2++) o[j2] = smem[(tc * 8 + j2) * 132 + ch];
        int n = nbase + ch;
        int h = n >> 6, d = n & 63;
        *(bf16x8*)(Vt + ((size_t)((bb * NHEAD + h) * HDIM + d)) * TSEQ +
                   tbase + pass * 64 + tc * 8) = o;
      }
    }
  }
}

// ---------------- GEMM (out-proj): 128x128 tile + pipeline + swizzle ---------
// R13 pipeline + the same conflict-free chunk swizzle as gemm1.
__global__ __launch_bounds__(256) void gemm_out(const bf16* __restrict__ A,
                                                const bf16* __restrict__ B,
                                                float* __restrict__ C,
                                                int M, int N, int K) {
  __shared__ bf16 smem[24576];  // 3 x (A 4096 + B 4096)
  const int t = threadIdx.x;
  const int w = t >> 6, l = t & 63, g = l >> 4, ln = l & 15;
  const int wm = (w >> 1) * 64, wn = (w & 1) * 64;
  const int m0 = blockIdx.x * 128, n0 = blockIdx.y * 128;
  const int r0 = t >> 2;
  const int kcs = ((t & 3) ^ ((t >> 3) & 3)) * 8;  // pre-swizzled source chunk
  const int rsl = ((ln >> 1) & 3) * 8;             // read-side slot xor (elems)

  f32x4 acc[4][4] = {};

#define STAGE_GO(buf, k0)                                                             \
  do {                                                                                \
    __builtin_amdgcn_global_load_lds(AS1(A + (size_t)(m0 + r0) * K + (k0) + kcs),     \
                                     AS3(&smem[(buf) * 8192 + t * 8]), 16, 0, 0);     \
    __builtin_amdgcn_global_load_lds(AS1(A + (size_t)(m0 + r0 + 64) * K + (k0) + kcs),\
                                     AS3(&smem[(buf) * 8192 + (t + 256) * 8]), 16, 0, 0); \
    __builtin_amdgcn_global_load_lds(AS1(B + (size_t)(n0 + r0) * K + (k0) + kcs),     \
                                     AS3(&smem[(buf) * 8192 + 4096 + t * 8]), 16, 0, 0);  \
    __builtin_amdgcn_global_load_lds(AS1(B + (size_t)(n0 + r0 + 64) * K + (k0) + kcs),\
                                     AS3(&smem[(buf) * 8192 + 4096 + (t + 256) * 8]), 16, 0, 0); \
  } while (0)

  STAGE_GO(0, 0);
  STAGE_GO(1, 32);
  asm volatile("s_waitcnt vmcnt(4) lgkmcnt(0)" ::: "memory");
  __builtin_amdgcn_s_barrier();
  asm volatile("" ::: "memory");

  for (int it = 0; it < 32; ++it) {
    const int cur = it % 3;
    if (it < 30) STAGE_GO((it + 2) % 3, (it + 2) * 32);
    const bf16* sa = &smem[cur * 8192];
    const bf16* sb = &smem[cur * 8192 + 4096];
    bf16x8 af[4], bfr[4];
#pragma unroll
    for (int i = 0; i < 4; i++) {
      af[i] = *(const bf16x8*)&sa[(wm + i * 16 + ln) * 32 + ((g * 8) ^ rsl)];
      bfr[i] = *(const bf16x8*)&sb[(wn + i * 16 + ln) * 32 + ((g * 8) ^ rsl)];
    }
#pragma unroll
    for (int i = 0; i < 4; i++)
#pragma unroll
      for (int j = 0; j < 4; j++)
        acc[i][j] = __builtin_amdgcn_mfma_f32_16x16x32_bf16(af[i], bfr[j], acc[i][j], 0, 0, 0);
    if (it < 30) {
      asm volatile("s_waitcnt vmcnt(4) lgkmcnt(0)" ::: "memory");
      __builtin_amdgcn_s_barrier();
      asm volatile("" ::: "memory");
    } else if (it == 30) {
      asm volatile("s_waitcnt vmcnt(0) lgkmcnt(0)" ::: "memory");
      __builtin_amdgcn_s_barrier();
      asm volatile("" ::: "memory");
    }
  }
#undef STAGE_GO

#pragma unroll
  for (int i = 0; i < 4; i++)
#pragma unroll
    for (int j = 0; j < 4; j++) {
      int row = m0 + wm + i * 16 + g * 4;
      int col = n0 + wn + j * 16 + ln;
#pragma unroll
      for (int r = 0; r < 4; r++)
        C[(size_t)(row + r) * N + col] = acc[i][j][r];
    }
}

// ---------------- Flash attention (causal), split-k x2, no-max exp2 ----------
// R7-EXACT version (best measured). 2-subtile variants closed after three
// losses (R5 occupancy, R9 spills, R10 clean-but-slower).
__global__ __launch_bounds__(1024, 4) void attn_fwd(const bf16* __restrict__ Q,
                                                    const bf16* __restrict__ K,
                                                    const bf16* __restrict__ Vt,
                                                    bf16* __restrict__ ctx) {
  __shared__ __align__(16) char smem_raw[65536];
  bf16* Ks = (bf16*)smem_raw;                   // [2][64*64]  16KB
  bf16* VTs = (bf16*)(smem_raw + 16384);        // [2][64*64]  16KB
  bf16* Ps = (bf16*)(smem_raw + 32768);         // [16][16*64] 32KB
  float* Mbuf = (float*)smem_raw;               // overlay, merge phase (32KB)
  float* Lbuf = (float*)(smem_raw + 32768);     // overlay, merge phase (2KB)

  const int t = threadIdx.x;
  const int w = t >> 6;                 // wave 0..15
  const int p = w >> 3;                 // parity group 0/1
  const int wq = w & 7;                 // q-subwave 0..7 (16 rows each)
  const int l = t & 63, g = l >> 4, ln = l & 15;
  const int bid = blockIdx.x;
  const int bh = bid & 31;              // head-locality: XCD = bh & 7
  const int qb0 = 15 - (bid >> 5);      // LPT: longest blocks first
  const size_t base = (size_t)bh * TSEQ * HDIM;

  const int q0 = qb0 * 128;
  const int qwb = q0 + wq * 16;         // this wave's q base
  const int dtile = qwb >> 6;           // = 2*qb0 + (wq>>2)
  const int q_g = qwb + ln;
  const int lswz = (ln & 7) * 8;        // read-side xor operand (elements)

  // staging: threads [0,512) stage group0's tile, [512,1024) group1's.
  const int ts = t >> 9;                // == p for this thread's waves
  const int tt = t & 511;
  const int r0 = tt >> 3, ch0 = (tt & 7) * 8;
  const int sidx = r0 * 64 + (((tt & 7) ^ (r0 & 7)) * 8);  // swizzled dst

  bf16x8 bq[2];
  bq[0] = *(const bf16x8*)(Q + base + (size_t)q_g * HDIM + g * 8);
  bq[1] = *(const bf16x8*)(Q + base + (size_t)q_g * HDIM + 32 + g * 8);

  // my group's tile sequence: kt = 2i + ts -> rows ts*64 + r0 + i*128
  const bf16* kp = K + base + (size_t)(ts * 64 + r0) * HDIM + ch0;
  const bf16* vp = Vt + base + (size_t)r0 * TSEQ + ts * 64 + ch0;
  bf16x8 kr = *(const bf16x8*)kp;
  bf16x8 vr = *(const bf16x8*)vp;

  f32x4 acc[4] = {};
  float l_run = 0.f;

  for (int i = 0; i <= qb0; i++) {
    __syncthreads();  // prev tiles' readers done
    *(bf16x8*)&Ks[ts * 4096 + sidx] = kr;
    *(bf16x8*)&VTs[ts * 4096 + sidx] = vr;
    __syncthreads();  // tiles visible
    if (i < qb0) {    // prefetch my group's next tile (rows +128)
      kr = *(const bf16x8*)(kp + (size_t)(i + 1) * 128 * HDIM);
      vr = *(const bf16x8*)(vp + (i + 1) * 128);
    }
    const int kt = 2 * i + p;
    if (kt <= dtile) {  // wave-uniform predicate (no barrier inside)
      f32x4 st[4] = {};
      __builtin_amdgcn_s_setprio(1);
#pragma unroll
      for (int step = 0; step < 2; step++)
#pragma unroll
        for (int mt = 0; mt < 4; mt++) {
          bf16x8 ak = *(const bf16x8*)&Ks[p * 4096 + (mt * 16 + ln) * 64 +
                                          ((step * 32 + g * 8) ^ lswz)];
          st[mt] = __builtin_amdgcn_mfma_f32_16x16x32_bf16(ak, bq[step], st[mt], 0, 0, 0);
        }
      __builtin_amdgcn_s_setprio(0);
      float vals[16];
      if (kt == dtile) {
#pragma unroll
        for (int mt = 0; mt < 4; mt++)
#pragma unroll
          for (int r = 0; r < 4; r++) {
            int kg = kt * 64 + mt * 16 + g * 4 + r;
            vals[mt * 4 + r] = (kg <= q_g) ? st[mt][r] : -INFINITY;
          }
      } else {
#pragma unroll
        for (int mt = 0; mt < 4; mt++)
#pragma unroll
          for (int r = 0; r < 4; r++) vals[mt * 4 + r] = st[mt][r];
      }
      float psum = 0.f;
#pragma unroll
      for (int i2 = 0; i2 < 16; i2++) {
        float pv = EXP2(vals[i2]);
        vals[i2] = pv;
        psum += pv;
      }
      psum += __shfl_xor(psum, 16);
      psum += __shfl_xor(psum, 32);
      l_run += psum;
#pragma unroll
      for (int mt = 0; mt < 4; mt++) {
        bf16x4 pk;
#pragma unroll
        for (int r = 0; r < 4; r++) pk[r] = (bf16)vals[mt * 4 + r];
        // k-col = mt*16 + g*4 -> col8 = mt*2 + (g>>1); swizzle col8 by ln&7
        *(bf16x4*)&Ps[w * 1024 + ln * 64 +
                      (((mt * 16 + (g >> 1) * 8) ^ lswz) + (g & 1) * 4)] = pk;
      }
      __builtin_amdgcn_s_setprio(1);
#pragma unroll
      for (int step = 0; step < 2; step++) {
        bf16x8 ap = *(const bf16x8*)&Ps[w * 1024 + ln * 64 + ((step * 32 + g * 8) ^ lswz)];
#pragma unroll
        for (int nt = 0; nt < 4; nt++) {
          bf16x8 bv = *(const bf16x8*)&VTs[p * 4096 + (nt * 16 + ln) * 64 +
                                           ((step * 32 + g * 8) ^ lswz)];
          acc[nt] = __builtin_amdgcn_mfma_f32_16x16x32_bf16(ap, bv, acc[nt], 0, 0, 0);
        }
      }
      __builtin_amdgcn_s_setprio(0);
    }
  }

  // ---- merge the two parity groups (overlay on dead K/V/Ps LDS) ----
  __syncthreads();  // loop reads done; staging area dead
  if (p == 1) {
#pragma unroll
    for (int nt = 0; nt < 4; nt++)
      *(f32x4*)&Mbuf[(wq * 64 + l) * 16 + nt * 4] = acc[nt];
    Lbuf[wq * 64 + l] = l_run;
  }
  __syncthreads();
  if (p == 0) {
#pragma unroll
    for (int nt = 0; nt < 4; nt++) acc[nt] += *(const f32x4*)&Mbuf[(wq * 64 + l) * 16 + nt * 4];
    l_run += Lbuf[wq * 64 + l];
    float inv = 1.0f / l_run;  // all 4 g-copies of a given ln hold the sum
    float lrow[4];
#pragma unroll
    for (int r = 0; r < 4; r++) lrow[r] = __shfl(inv, g * 4 + r, 64);
    const int b = bh >> 4, h = bh & (NHEAD - 1);
#pragma unroll
    for (int nt = 0; nt < 4; nt++)
#pragma unroll
      for (int r = 0; r < 4; r++) {
        int q = qwb + g * 4 + r;
        ctx[(size_t)(b * TSEQ + q) * CDIM + h * HDIM + nt * 16 + ln] =
            (bf16)(acc[nt][r] * lrow[r]);
      }
  }
}

extern "C" void kernel_launch(void* const* d_in, const int* in_sizes, int n_in,
                              void* d_out, int out_size, void* d_ws, size_t ws_size,
                              hipStream_t stream) {
  const float* x = (const float*)d_in[0];
  const float* cosb = (const float*)d_in[1];
  const float* sinb = (const float*)d_in[2];
  // d_in[3] = mask (bool) — unused; causality derived from indices
  const float* Wqkv = (const float*)d_in[4];
  const float* Wout = (const float*)d_in[5];
  float* out = (float*)d_out;

  // ws layout (42 MB):
  //  [0,8M)          x_bf -> ctx (x_bf dead after gemm1)
  //  [8M,14M)        Wqkv_bf (dead after gemm1)
  //  [14M,16M)       Wout_bf (live until gemm_out)
  //  [16M,24M)       Qb    [24M,32M) Kb    [32M,40M) Vt
  char* ws = (char*)d_ws;
  bf16* x_bf = (bf16*)ws;
  bf16* ctx = (bf16*)ws;
  bf16* Wqkv_bf = (bf16*)(ws + 8388608);
  bf16* Wout_bf = (bf16*)(ws + 14680064);
  bf16* Qb = (bf16*)(ws + 16777216);
  bf16* Kb = (bf16*)(ws + 25165824);
  bf16* Vt = (bf16*)(ws + 33554432);

  // one cast launch for all three fp32 inputs
  cast3_bf16<<<(4194304 + 3145728 + 1048576) / 8 / 256, 256, 0, stream>>>(
      x, 4194304, Wqkv, 3145728, Wout, 1048576, x_bf, Wqkv_bf, Wout_bf);
  // gemm1 + rope + V-transpose fused (counted-vmcnt pipeline + swizzle)
  gemm_qkv_rope<<<dim3(32, 24), 256, 0, stream>>>(x_bf, Wqkv_bf, cosb, sinb, Qb, Kb, Vt);
  // causal flash attention, split-k x2 -> ctx [B*T, C] (overwrites x_bf)
  attn_fwd<<<512, 1024, 0, stream>>>(Qb, Kb, Vt, ctx);
  // out = ctx @ Wout^T (fp32 out), 128^2 tile + pipeline + swizzle
  gemm_out<<<dim3(32, 8), 256, 0, stream>>>(ctx, Wout_bf, out, 4096, 1024, 1024);
}